// Round 18
// baseline (202.727 us; speedup 1.0000x reference)
//
#include <hip/hip_runtime.h>
#include <stdint.h>

#define DEV __device__ __forceinline__

using f32x4  = __attribute__((ext_vector_type(4))) float;
using f32x16 = __attribute__((ext_vector_type(16))) float;
using bf16x8 = __attribute__((ext_vector_type(8))) short;

DEV ushort f2bf(float f){
  uint32_t u = __float_as_uint(f);
  u += 0x7FFFu + ((u >> 16) & 1u);
  return (ushort)(u >> 16);
}
DEV float bf2f(ushort h){ return __uint_as_float(((uint32_t)h) << 16); }

DEV void async16(const void* g, void* l){
  __builtin_amdgcn_global_load_lds(
      (const __attribute__((address_space(1))) void*)g,
      (__attribute__((address_space(3))) void*)l, 16, 0, 0);
}

union FU { uint4 u; bf16x8 v; };
DEV bf16x8 as_bf16x8(uint a, uint b, uint c, uint d){ FU f; f.u = make_uint4(a,b,c,d); return f.v; }

// ---------- f32 -> bf16 input conversion, both streams in ONE launch ----------
__global__ __launch_bounds__(256) void k_conv_in(const float* __restrict__ a, const float* __restrict__ bsrc,
                                                 ushort* __restrict__ dst){
  int bid = blockIdx.x;                       // 3072 blocks: 0..1535 = cond, 1536.. = x
  const float* src = (bid < 1536) ? a : bsrc;
  ushort* d = dst + ((bid < 1536) ? 0 : 3145728);
  int i = (((bid >= 1536) ? bid - 1536 : bid) * 256 + threadIdx.x) * 8;
  float4 va = *(const float4*)(src + i);
  float4 vb = *(const float4*)(src + i + 4);
  union { ushort s[8]; uint4 q; } o;
  o.s[0]=f2bf(va.x); o.s[1]=f2bf(va.y); o.s[2]=f2bf(va.z); o.s[3]=f2bf(va.w);
  o.s[4]=f2bf(vb.x); o.s[5]=f2bf(vb.y); o.s[6]=f2bf(vb.z); o.s[7]=f2bf(vb.w);
  *(uint4*)(d + i) = o.q;
}

// ---------- weight transpose+convert: W[k][n] f32 -> Wt[n][k] bf16 (plain) ----------
__global__ __launch_bounds__(256) void k_transpose_w(
    const float* w0, const float* w1, const float* w2, const float* w3,
    const float* w4, const float* w5, const float* w6, const float* w7,
    ushort* __restrict__ dst){
  __shared__ float tile[32][33];
  int z = blockIdx.z;
  const float* src = (z==0)?w0:(z==1)?w1:(z==2)?w2:(z==3)?w3:(z==4)?w4:(z==5)?w5:(z==6)?w6:w7;
  int n0 = blockIdx.x * 32;
  int k0 = blockIdx.y * 32;
  int tx = threadIdx.x;   // 0..31
  int ty = threadIdx.y;   // 0..7
  for (int j = 0; j < 4; ++j)
    tile[ty + j*8][tx] = src[(size_t)(k0 + ty + j*8) * 1536 + n0 + tx];
  __syncthreads();
  ushort* d = dst + (size_t)z * 1536 * 1536;
  for (int j = 0; j < 4; ++j){
    int n = n0 + ty + j*8;
    int k = k0 + tx;
    d[(size_t)n * 1536 + k] = f2bf(tile[tx][ty + j*8]);
  }
}

// ---------- QKV GEMM: 256x288, BK=64, dbuf, ONE barrier per K-tile (R13-proven) ----------
__global__ __launch_bounds__(512, 1) void k_gemm_qkv(const ushort* __restrict__ inb,
                                                     const ushort* __restrict__ Wt,
                                                     ushort* __restrict__ Y){
  __shared__ ushort As[2][16384];   // [buf][256 rows][64 k]
  __shared__ ushort Bs[2][18432];   // [buf][288 rows][64 k]
  int f = blockIdx.x;
  int nid = (f & 7) * 32 + (f >> 3);     // XCD-chunked: each XCD owns 8my x 4nx
  int z = nid >> 7; int r = nid & 127;
  int my = (r >> 2) & 7, nx = (r >> 5) * 4 + (r & 3);
  const ushort* A = inb + (size_t)z * 2048 * 1536 + (size_t)(my * 256) * 1536;
  const ushort* B = Wt  + (size_t)z * 4608 * 1536 + (size_t)(nx * 288) * 1536;
  ushort* Yt = Y + (size_t)z * 2048 * 4608 + (size_t)(my * 256) * 4608 + nx * 288;
  int tid = threadIdx.x;
  int w = tid >> 6, lane = tid & 63;
  int g = lane >> 4, fr = lane & 15;
  int wm = (w >> 1) * 64, wn = (w & 1) * 144;

  f32x4 acc[4][9] = {};

  auto stageA = [&](int b, int kt){
#pragma unroll
    for (int s = 0; s < 4; ++s){
      int c = s * 512 + tid;
      int row = c >> 3, ch = c & 7;
      async16(A + (size_t)row * 1536 + kt + ((ch ^ (row & 7)) * 8), &As[b][c * 8]);
    }
  };
  auto stageB = [&](int b, int kt){
#pragma unroll
    for (int s = 0; s < 4; ++s){
      int c = s * 512 + tid;
      int row = c >> 3, ch = c & 7;
      async16(B + (size_t)row * 1536 + kt + ((ch ^ (row & 7)) * 8), &Bs[b][c * 8]);
    }
    if (tid < 256){                     // 288-row tail: waves 0..3 (wave-uniform)
      int c = 2048 + tid;
      int row = c >> 3, ch = c & 7;
      async16(B + (size_t)row * 1536 + kt + ((ch ^ (row & 7)) * 8), &Bs[b][c * 8]);
    }
  };

  stageA(0, 0); stageB(0, 0);
  asm volatile("s_waitcnt vmcnt(0)" ::: "memory");
  __builtin_amdgcn_s_barrier();
  asm volatile("" ::: "memory");

  for (int t = 0; t < 24; ++t){
    int cur = t & 1, nxt = cur ^ 1;
    if (t < 23){ stageA(nxt, (t+1) * 64); stageB(nxt, (t+1) * 64); }
#pragma unroll
    for (int ks = 0; ks < 2; ++ks){
      bf16x8 af[4], bf[9];
#pragma unroll
      for (int j = 0; j < 4; ++j){
        int row = wm + j*16 + fr;
        af[j] = *(const bf16x8*)&As[cur][row*64 + (((ks*4 + g) ^ (row & 7)) << 3)];
      }
#pragma unroll
      for (int ni = 0; ni < 9; ++ni){
        int row = wn + ni*16 + fr;
        bf[ni] = *(const bf16x8*)&Bs[cur][row*64 + (((ks*4 + g) ^ (row & 7)) << 3)];
      }
      __builtin_amdgcn_s_setprio(1);
#pragma unroll
      for (int ni = 0; ni < 9; ++ni){
#pragma unroll
        for (int j = 0; j < 4; ++j)
          acc[j][ni] = __builtin_amdgcn_mfma_f32_16x16x32_bf16(af[j], bf[ni], acc[j][ni], 0, 0, 0);
      }
      __builtin_amdgcn_s_setprio(0);
    }
    if (t < 23) asm volatile("s_waitcnt vmcnt(0)" ::: "memory");
    asm volatile("s_waitcnt lgkmcnt(0)" ::: "memory");
    __builtin_amdgcn_s_barrier();
    asm volatile("" ::: "memory");
  }

#pragma unroll
  for (int mi = 0; mi < 4; ++mi)
#pragma unroll
    for (int ni = 0; ni < 9; ++ni)
#pragma unroll
      for (int rr = 0; rr < 4; ++rr)
        Yt[(size_t)(wm + mi*16 + g*4 + rr) * 4608 + wn + ni*16 + fr] = f2bf(acc[mi][ni][rr]);
}

// ---------- proj GEMM: 128x128, BK=64, dbuf, ONE barrier per K-tile (R15-proven) ----------
__global__ __launch_bounds__(256) void k_gemm_proj(const ushort* __restrict__ AO, const ushort* __restrict__ Wtp,
                                                   float* __restrict__ out){
  __shared__ ushort As[2][8192];
  __shared__ ushort Bs[2][8192];
  int f = blockIdx.x;                      // 384 blocks (= 8*48)
  int nid = (f & 7) * 48 + (f >> 3);
  int z = nid / 96; int rr2 = nid - z * 96;
  int by = rr2 / 12; int bx = rr2 - by * 12;
  int s = z >> 1, bb = z & 1;
  const ushort* A  = AO  + (size_t)(bb*2048 + s*1024 + by*128) * 1536;
  const ushort* Bt = Wtp + (size_t)s * 1536 * 1536 + (size_t)(bx*128) * 1536;
  float* C = out + (size_t)(s*2048 + bb*1024 + by*128) * 1536 + bx*128;
  int tid = threadIdx.x;
  int w = tid >> 6, lane = tid & 63;
  int g = lane >> 4, fr = lane & 15;
  int wm = (w >> 1) * 64, wn = (w & 1) * 64;
  f32x4 acc[4][4] = {};

  auto stage = [&](int b, int kt){
#pragma unroll
    for (int i = 0; i < 4; ++i){
      int c = i * 256 + tid;
      int row = c >> 3, ch = c & 7;
      int src8 = (ch ^ (row & 7)) * 8;
      async16(A  + (size_t)row * 1536 + kt + src8, &As[b][c * 8]);
      async16(Bt + (size_t)row * 1536 + kt + src8, &Bs[b][c * 8]);
    }
  };

  stage(0, 0);
  asm volatile("s_waitcnt vmcnt(0)" ::: "memory");
  __builtin_amdgcn_s_barrier();
  asm volatile("" ::: "memory");

  for (int t = 0; t < 24; ++t){
    int cur = t & 1, nxt = cur ^ 1;
    if (t < 23) stage(nxt, (t+1) * 64);
#pragma unroll
    for (int ks = 0; ks < 2; ++ks){
      bf16x8 af[4], bf[4];
#pragma unroll
      for (int mi = 0; mi < 4; ++mi){
        int row = wm + mi*16 + fr;
        af[mi] = *(const bf16x8*)&As[cur][row*64 + (((ks*4 + g) ^ (row & 7)) << 3)];
      }
#pragma unroll
      for (int ni = 0; ni < 4; ++ni){
        int row = wn + ni*16 + fr;
        bf[ni] = *(const bf16x8*)&Bs[cur][row*64 + (((ks*4 + g) ^ (row & 7)) << 3)];
      }
      __builtin_amdgcn_s_setprio(1);
#pragma unroll
      for (int mi = 0; mi < 4; ++mi)
#pragma unroll
        for (int ni = 0; ni < 4; ++ni)
          acc[mi][ni] = __builtin_amdgcn_mfma_f32_16x16x32_bf16(af[mi], bf[ni], acc[mi][ni], 0, 0, 0);
      __builtin_amdgcn_s_setprio(0);
    }
    if (t < 23) asm volatile("s_waitcnt vmcnt(0)" ::: "memory");
    asm volatile("s_waitcnt lgkmcnt(0)" ::: "memory");
    __builtin_amdgcn_s_barrier();
    asm volatile("" ::: "memory");
  }

  int cr = (lane >> 4) * 4, cc2 = lane & 15;
#pragma unroll
  for (int mi = 0; mi < 4; ++mi)
#pragma unroll
    for (int ni = 0; ni < 4; ++ni)
#pragma unroll
      for (int r = 0; r < 4; ++r)
        C[(size_t)(wm + mi*16 + cr + r) * 1536 + wn + ni*16 + cc2] = acc[mi][ni][r];
}

// ---------- fused RMSNorm + 3D RoPE, LDS-staged coalesced row load (R17-proven) ----------
__global__ __launch_bounds__(256) void k_norm_rope(
    const ushort* __restrict__ Y,
    const float* __restrict__ qn_c, const float* __restrict__ kn_c,
    const float* __restrict__ qn_x, const float* __restrict__ kn_x,
    ushort* __restrict__ Qb, ushort* __restrict__ Kb){
  int r = blockIdx.x;          // row within stream, 0..2047
  int z = blockIdx.y;          // stream: 0 cond, 1 x
  const ushort* y = Y + ((size_t)z * 2048 + r) * 4608;
  const float* qw = z ? qn_x : qn_c;
  const float* kw = z ? kn_x : kn_c;
  int b = r >> 10;
  int l = (z << 10) + (r & 1023);        // joint sequence position
  int tid = threadIdx.x;
  __shared__ uint4 yl4[576];             // staged full row (4608 ushorts)
  ushort* yl = (ushort*)yl4;
  __shared__ float cs[48], sn[48];
  {
    const uint4* ysrc = (const uint4*)y;
    yl4[tid]       = ysrc[tid];
    yl4[tid + 256] = ysrc[tid + 256];
    if (tid < 64) yl4[tid + 512] = ysrc[tid + 512];
  }
  if (tid < 48){
    int axis = tid >> 4, fj = tid & 15;
    int pos = (axis == 0) ? (l >> 10) : ((axis == 1) ? ((l >> 5) & 31) : (l & 31));
    float inv = __expf(-(float)fj * 0.5756462732485114f);  // 10000^(-fj/16)
    float a = (float)pos * inv;
    sn[tid] = sinf(a); cs[tid] = cosf(a);
  }
  __syncthreads();
  float yq1[3], yq2[3], yk1[3], yk2[3];
  float ssq = 0.f, ssk = 0.f;
#pragma unroll
  for (int i = 0; i < 3; ++i){
    int p = tid + i*256;                 // pair index 0..767
    int head = p / 48, rem = p % 48;
    int c1 = head*96 + (rem >> 4)*32 + (rem & 15);
    float a1 = bf2f(yl[c1]),        a2 = bf2f(yl[c1 + 16]);
    float b1 = bf2f(yl[1536 + c1]), b2 = bf2f(yl[1536 + c1 + 16]);
    yq1[i]=a1; yq2[i]=a2; yk1[i]=b1; yk2[i]=b2;
    ssq += a1*a1 + a2*a2;
    ssk += b1*b1 + b2*b2;
  }
#pragma unroll
  for (int mm = 1; mm < 64; mm <<= 1){
    ssq += __shfl_xor(ssq, mm);
    ssk += __shfl_xor(ssk, mm);
  }
  __shared__ float red[8];
  int w = tid >> 6;
  if ((tid & 63) == 0){ red[w] = ssq; red[4 + w] = ssk; }
  __syncthreads();
  float scq = rsqrtf((red[0]+red[1]+red[2]+red[3]) * (1.f/1536.f) + 1e-6f);
  float sck = rsqrtf((red[4]+red[5]+red[6]+red[7]) * (1.f/1536.f) + 1e-6f);
  float scqS = scq * 0.1020620726159658f;   // fold SCALE = 96^-0.5 into Q (R7-proven; NO log2e)
#pragma unroll
  for (int i = 0; i < 3; ++i){
    int p = tid + i*256;
    int head = p / 48, rem = p % 48;
    int axis = rem >> 4, fj = rem & 15;
    int c1 = head*96 + axis*32 + fj;
    float c = cs[rem], s = sn[rem];
    size_t rowb = ((size_t)(b*16 + head) * 2048 + l) * 96;
    float a1 = yq1[i] * scqS * qw[c1], a2 = yq2[i] * scqS * qw[c1 + 16];
    Qb[rowb + axis*32 + fj]      = f2bf(a1*c - a2*s);
    Qb[rowb + axis*32 + fj + 16] = f2bf(a2*c + a1*s);
    float b1 = yk1[i] * sck * kw[c1], b2 = yk2[i] * sck * kw[c1 + 16];
    int d1 = axis*32 + fj;
    Kb[rowb + d1]      = f2bf(b1*c - b2*s);
    Kb[rowb + d1 + 16] = f2bf(b2*c + b1*s);
  }
}

// ---------- V transpose per head, reading directly from Y: [l][4608] -> [d][2048] ----------
__global__ __launch_bounds__(256) void k_transpose_v(const ushort* __restrict__ Y, ushort* __restrict__ Vt){
  __shared__ ushort t[32][33];
  int bh = blockIdx.z;
  int b = bh >> 4, head = bh & 15;
  int c0 = blockIdx.x * 32;   // d tile within head (0,32,64)
  int l0 = blockIdx.y * 32;   // l tile (32 | 1024 -> never crosses stream boundary)
  int z = l0 >> 10;
  const ushort* src = Y + ((size_t)(z*2048 + b*1024 + (l0 & 1023))) * 4608 + 3072 + head*96 + c0;
  ushort* dst = Vt + (size_t)bh * 96 * 2048;
  int tx = threadIdx.x, ty = threadIdx.y;
  for (int j = 0; j < 4; ++j)
    t[ty + j*8][tx] = src[(size_t)(ty + j*8) * 4608 + tx];
  __syncthreads();
  for (int j = 0; j < 4; ++j)
    dst[(size_t)(c0 + ty + j*8) * 2048 + l0 + tx] = t[tx][ty + j*8];
}

// ---------- flash attention: R13 structure + MFMA-ones denominator (fmaf exp kept) ----------
// Denominator: one extra mfma per (ni,ks) with B = 1.0 in column 0 -> o3[r] at lane
// (h, c=0) accumulates sum_k P[q][k] across all tiles. Deletes the 30-VALU dpart chain.
__global__ __launch_bounds__(256, 2) void k_attn(const ushort* __restrict__ Qb, const ushort* __restrict__ Kb,
                                                 const ushort* __restrict__ Vt, ushort* __restrict__ AO){
  __shared__ ushort Ks[2][6400];   // 64 x (stride 100): bank-step period 16 -> 2-way free on b64
  __shared__ ushort Vs[2][6528];   // 96 x (stride 68), chunk-XOR swizzle
  int id = blockIdx.x;
  int nid = (id & 7) * 64 + (id >> 3);   // XCD-chunked
  int qt = nid & 15, bh = nid >> 4;
  int b = bh >> 4, head = bh & 15;
  const ushort* Qh = Qb + (size_t)bh * 2048 * 96;
  const ushort* Kh = Kb + (size_t)bh * 2048 * 96;
  const ushort* Vh = Vt + (size_t)bh * 96 * 2048;
  int tid = threadIdx.x;
  int w = tid >> 6, lane = tid & 63;
  int h = lane >> 5, c = lane & 31;
  int q0 = qt * 128 + w * 32;

  bf16x8 qf[6];
#pragma unroll
  for (int kb = 0; kb < 6; ++kb)
    qf[kb] = *(const bf16x8*)(Qh + (size_t)(q0 + c) * 96 + kb*16 + h*8);

  // ones B-frag for denominator mfma: column 0 = 1.0, other columns 0
  uint ov = (c == 0) ? 0x3F803F80u : 0u;
  bf16x8 onesf = as_bf16x8(ov, ov, ov, ov);

  int gko[3], lko[3], gvo[3], lvo[3];
#pragma unroll
  for (int i = 0; i < 3; ++i){
    int fc = i*256 + tid;
    int krow = (fc * 683) >> 13;          // /12 exact for fc<2028
    int kc8  = (fc - krow*12) * 8;
    gko[i] = krow*96 + kc8;
    lko[i] = krow*100 + kc8;
    int vrow = fc >> 3;
    int vc8  = (fc & 7) * 8;
    gvo[i] = vrow*2048 + vc8;
    lvo[i] = vrow*68 + (vc8 ^ ((vrow & 7) << 3));   // chunk XOR swizzle
  }
  uint4 kst[3], vst[3];
  f32x16 o[3] = {};
  f32x16 o3 = {};          // denominator accumulator
  f32x16 sa[2];

  auto LOADG = [&](int tt){
#pragma unroll
    for (int i = 0; i < 3; ++i){
      kst[i] = *(const uint4*)(Kh + (size_t)tt*6144 + gko[i]);
      vst[i] = *(const uint4*)(Vh + (size_t)tt*64 + gvo[i]);
    }
  };
  auto WRITE = [&](int buf){
#pragma unroll
    for (int i = 0; i < 3; ++i){
      *(uint2*)(&Ks[buf][lko[i]])     = make_uint2(kst[i].x, kst[i].y);
      *(uint2*)(&Ks[buf][lko[i] + 4]) = make_uint2(kst[i].z, kst[i].w);
      *(uint2*)(&Vs[buf][lvo[i]])     = make_uint2(vst[i].x, vst[i].y);
      *(uint2*)(&Vs[buf][lvo[i] + 4]) = make_uint2(vst[i].z, vst[i].w);
    }
  };
  auto QK = [&](f32x16* out, int buf){
#pragma unroll
    for (int ni = 0; ni < 2; ++ni){
      f32x16 a = {};
#pragma unroll
      for (int kb = 0; kb < 6; ++kb){
        const ushort* kp = &Ks[buf][(ni*32 + c)*100 + kb*16 + h*8];
        uint2 lo = *(const uint2*)kp;
        uint2 hi = *(const uint2*)(kp + 4);
        a = __builtin_amdgcn_mfma_f32_32x32x16_bf16(as_bf16x8(lo.x, lo.y, hi.x, hi.y), qf[kb], a, 0, 0, 0);
      }
      out[ni] = a;
    }
  };
  auto PV = [&](bf16x8 pf[2][2], int buf){
#pragma unroll
    for (int ni = 0; ni < 2; ++ni)
#pragma unroll
      for (int ks = 0; ks < 2; ++ks){
#pragma unroll
        for (int dt = 0; dt < 3; ++dt){
          int chunk = 4*ni + 2*ks + h;
          const ushort* vp = &Vs[buf][(dt*32 + c)*68 + ((chunk ^ (c & 7)) << 3)];
          uint2 lo = *(const uint2*)vp;
          uint2 hi = *(const uint2*)(vp + 4);
          o[dt] = __builtin_amdgcn_mfma_f32_32x32x16_bf16(pf[ni][ks],
                    as_bf16x8(lo.x, lo.y, hi.x, hi.y), o[dt], 0, 0, 0);
        }
        o3 = __builtin_amdgcn_mfma_f32_32x32x16_bf16(pf[ni][ks], onesf, o3, 0, 0, 0);
      }
  };

  // prologue: KV(0) -> buf0; issue KV(1); QK(0)
  LOADG(0);
  WRITE(0);
  LOADG(1);
  asm volatile("s_waitcnt lgkmcnt(0)" ::: "memory");
  __builtin_amdgcn_s_barrier();
  asm volatile("" ::: "memory");
  QK(sa, 0);

  for (int t = 0; t < 32; ++t){
    int cur = t & 1, nxt = cur ^ 1;
    if (t < 31) WRITE(nxt);            // KV(t+1) regs -> buf[nxt]
    if (t < 30) LOADG(t + 2);          // issue KV(t+2) global loads
    asm volatile("s_waitcnt lgkmcnt(0)" ::: "memory");
    __builtin_amdgcn_s_barrier();
    asm volatile("" ::: "memory");

    // softmax(sa) -> pf  (R7-proven: p = exp2(sa*log2e - 10*log2e); offset cancels in O/den)
    bf16x8 pf[2][2];
#pragma unroll
    for (int ni = 0; ni < 2; ++ni){
      float p[16];
#pragma unroll
      for (int e = 0; e < 16; ++e){
        float x = fmaf(sa[ni][e], 1.44269504f, -14.4269504f);
        asm("v_exp_f32 %0, %1" : "=v"(p[e]) : "v"(x));
      }
      uint u[8];
#pragma unroll
      for (int e = 0; e < 8; ++e)
        asm("v_cvt_pk_bf16_f32 %0, %1, %2" : "=v"(u[e]) : "v"(p[2*e]), "v"(p[2*e+1]));
      asm("v_permlane32_swap_b32 %0, %1" : "+v"(u[0]), "+v"(u[2]));
      asm("v_permlane32_swap_b32 %0, %1" : "+v"(u[1]), "+v"(u[3]));
      asm("v_permlane32_swap_b32 %0, %1" : "+v"(u[4]), "+v"(u[6]));
      asm("v_permlane32_swap_b32 %0, %1" : "+v"(u[5]), "+v"(u[7]));
      pf[ni][0] = as_bf16x8(u[0], u[1], u[2], u[3]);   // k = ni*32 + [0,16)
      pf[ni][1] = as_bf16x8(u[4], u[5], u[6], u[7]);   // k = ni*32 + [16,32)
    }

    if (t < 31){
      f32x16 na[2];
      QK(na, nxt);                     // QK(t+1) — overlaps softmax above
      PV(pf, cur);
      sa[0] = na[0]; sa[1] = na[1];
    } else {
      PV(pf, cur);
    }
    asm volatile("" ::: "memory");
    __builtin_amdgcn_s_barrier();
    asm volatile("" ::: "memory");
  }

#pragma unroll
  for (int r = 0; r < 16; ++r){
    int qloc = (r & 3) + 8*(r >> 2) + 4*h;
    float den = __shfl(o3[r], h * 32);       // lane (h, c=0) holds sum_k P[qloc][k]
    float dinv = __builtin_amdgcn_rcpf(den);
    size_t rowoff = ((size_t)b * 2048 + q0 + qloc) * 1536 + head * 96;
#pragma unroll
    for (int dt = 0; dt < 3; ++dt){
      float val = o[dt][r] * dinv;
      uint pk; asm("v_cvt_pk_bf16_f32 %0, %1, %2" : "=v"(pk) : "v"(val), "v"(val));
      AO[rowoff + dt*32 + c] = (ushort)pk;
    }
  }
}

extern "C" void kernel_launch(void* const* d_in, const int* in_sizes, int n_in,
                              void* d_out, int out_size, void* d_ws, size_t ws_size,
                              hipStream_t stream){
  const float* cond = (const float*)d_in[0];
  const float* x    = (const float*)d_in[1];
  const float* wq_c = (const float*)d_in[2];
  const float* wk_c = (const float*)d_in[3];
  const float* wv_c = (const float*)d_in[4];
  const float* qn_c = (const float*)d_in[5];
  const float* kn_c = (const float*)d_in[6];
  const float* wp_c = (const float*)d_in[7];
  const float* wq_x = (const float*)d_in[8];
  const float* wk_x = (const float*)d_in[9];
  const float* wv_x = (const float*)d_in[10];
  const float* qn_x = (const float*)d_in[11];
  const float* kn_x = (const float*)d_in[12];
  const float* wp_x = (const float*)d_in[13];

  char* ws = (char*)d_ws;
  ushort* inb = (ushort*)(ws);                 // [2][2048][1536] bf16 (later reused as AO)
  ushort* Wt  = (ushort*)(ws + 12582912ll);    // [12288][1536] bf16 (qkv_c, qkv_x, proj_c, proj_x)
  ushort* Y   = (ushort*)(ws + 50331648ll);    // [2][2048][4608] bf16
  ushort* Qb  = (ushort*)(ws + 88080384ll);    // [32][2048][96] (SCALE folded)
  ushort* Kb  = (ushort*)(ws + 100663296ll);   // [32][2048][96] plain
  ushort* Vt  = (ushort*)(ws + 113246208ll);   // [32][96][2048]
  ushort* AO  = inb;                           // [2][2048][1536] bf16 plain

  k_conv_in<<<3072, 256, 0, stream>>>(cond, x, inb);
  k_transpose_w<<<dim3(48,48,8), dim3(32,8), 0, stream>>>(wq_c, wk_c, wv_c, wq_x, wk_x, wv_x, wp_c, wp_x, Wt);
  k_gemm_qkv<<<256, 512, 0, stream>>>(inb, Wt, Y);
  k_norm_rope<<<dim3(2048,2), 256, 0, stream>>>(Y, qn_c, kn_c, qn_x, kn_x, Qb, Kb);
  k_transpose_v<<<dim3(3,64,32), dim3(32,8), 0, stream>>>(Y, Vt);
  k_attn<<<512, 256, 0, stream>>>(Qb, Kb, Vt, AO);
  k_gemm_proj<<<384, 256, 0, stream>>>(AO, Wt + (size_t)9216*1536, (float*)d_out);
  (void)in_sizes; (void)n_in; (void)out_size; (void)ws_size;
}

// Round 19
// 198.201 us; speedup vs baseline: 1.0228x; 1.0228x over previous
//
#include <hip/hip_runtime.h>
#include <stdint.h>

#define DEV __device__ __forceinline__

using f32x4  = __attribute__((ext_vector_type(4))) float;
using f32x16 = __attribute__((ext_vector_type(16))) float;
using bf16x8 = __attribute__((ext_vector_type(8))) short;

DEV ushort f2bf(float f){
  uint32_t u = __float_as_uint(f);
  u += 0x7FFFu + ((u >> 16) & 1u);
  return (ushort)(u >> 16);
}
DEV float bf2f(ushort h){ return __uint_as_float(((uint32_t)h) << 16); }

DEV void async16(const void* g, void* l){
  __builtin_amdgcn_global_load_lds(
      (const __attribute__((address_space(1))) void*)g,
      (__attribute__((address_space(3))) void*)l, 16, 0, 0);
}

union FU { uint4 u; bf16x8 v; };
DEV bf16x8 as_bf16x8(uint a, uint b, uint c, uint d){ FU f; f.u = make_uint4(a,b,c,d); return f.v; }

// ---------- f32 -> bf16 input conversion, both streams in ONE launch (R18-proven) ----------
__global__ __launch_bounds__(256) void k_conv_in(const float* __restrict__ a, const float* __restrict__ bsrc,
                                                 ushort* __restrict__ dst){
  int bid = blockIdx.x;                       // 3072 blocks: 0..1535 = cond, 1536.. = x
  const float* src = (bid < 1536) ? a : bsrc;
  ushort* d = dst + ((bid < 1536) ? 0 : 3145728);
  int i = (((bid >= 1536) ? bid - 1536 : bid) * 256 + threadIdx.x) * 8;
  float4 va = *(const float4*)(src + i);
  float4 vb = *(const float4*)(src + i + 4);
  union { ushort s[8]; uint4 q; } o;
  o.s[0]=f2bf(va.x); o.s[1]=f2bf(va.y); o.s[2]=f2bf(va.z); o.s[3]=f2bf(va.w);
  o.s[4]=f2bf(vb.x); o.s[5]=f2bf(vb.y); o.s[6]=f2bf(vb.z); o.s[7]=f2bf(vb.w);
  *(uint4*)(d + i) = o.q;
}

// ---------- weight transpose+convert: W[k][n] f32 -> Wt[n][k] bf16 (plain) ----------
__global__ __launch_bounds__(256) void k_transpose_w(
    const float* w0, const float* w1, const float* w2, const float* w3,
    const float* w4, const float* w5, const float* w6, const float* w7,
    ushort* __restrict__ dst){
  __shared__ float tile[32][33];
  int z = blockIdx.z;
  const float* src = (z==0)?w0:(z==1)?w1:(z==2)?w2:(z==3)?w3:(z==4)?w4:(z==5)?w5:(z==6)?w6:w7;
  int n0 = blockIdx.x * 32;
  int k0 = blockIdx.y * 32;
  int tx = threadIdx.x;   // 0..31
  int ty = threadIdx.y;   // 0..7
  for (int j = 0; j < 4; ++j)
    tile[ty + j*8][tx] = src[(size_t)(k0 + ty + j*8) * 1536 + n0 + tx];
  __syncthreads();
  ushort* d = dst + (size_t)z * 1536 * 1536;
  for (int j = 0; j < 4; ++j){
    int n = n0 + ty + j*8;
    int k = k0 + tx;
    d[(size_t)n * 1536 + k] = f2bf(tile[tx][ty + j*8]);
  }
}

// ---------- QKV GEMM: 256x288, BK=64, dbuf, ONE barrier per K-tile (R13-proven) ----------
__global__ __launch_bounds__(512, 1) void k_gemm_qkv(const ushort* __restrict__ inb,
                                                     const ushort* __restrict__ Wt,
                                                     ushort* __restrict__ Y){
  __shared__ ushort As[2][16384];   // [buf][256 rows][64 k]
  __shared__ ushort Bs[2][18432];   // [buf][288 rows][64 k]
  int f = blockIdx.x;
  int nid = (f & 7) * 32 + (f >> 3);     // XCD-chunked: each XCD owns 8my x 4nx
  int z = nid >> 7; int r = nid & 127;
  int my = (r >> 2) & 7, nx = (r >> 5) * 4 + (r & 3);
  const ushort* A = inb + (size_t)z * 2048 * 1536 + (size_t)(my * 256) * 1536;
  const ushort* B = Wt  + (size_t)z * 4608 * 1536 + (size_t)(nx * 288) * 1536;
  ushort* Yt = Y + (size_t)z * 2048 * 4608 + (size_t)(my * 256) * 4608 + nx * 288;
  int tid = threadIdx.x;
  int w = tid >> 6, lane = tid & 63;
  int g = lane >> 4, fr = lane & 15;
  int wm = (w >> 1) * 64, wn = (w & 1) * 144;

  f32x4 acc[4][9] = {};

  auto stageA = [&](int b, int kt){
#pragma unroll
    for (int s = 0; s < 4; ++s){
      int c = s * 512 + tid;
      int row = c >> 3, ch = c & 7;
      async16(A + (size_t)row * 1536 + kt + ((ch ^ (row & 7)) * 8), &As[b][c * 8]);
    }
  };
  auto stageB = [&](int b, int kt){
#pragma unroll
    for (int s = 0; s < 4; ++s){
      int c = s * 512 + tid;
      int row = c >> 3, ch = c & 7;
      async16(B + (size_t)row * 1536 + kt + ((ch ^ (row & 7)) * 8), &Bs[b][c * 8]);
    }
    if (tid < 256){                     // 288-row tail: waves 0..3 (wave-uniform)
      int c = 2048 + tid;
      int row = c >> 3, ch = c & 7;
      async16(B + (size_t)row * 1536 + kt + ((ch ^ (row & 7)) * 8), &Bs[b][c * 8]);
    }
  };

  stageA(0, 0); stageB(0, 0);
  asm volatile("s_waitcnt vmcnt(0)" ::: "memory");
  __builtin_amdgcn_s_barrier();
  asm volatile("" ::: "memory");

  for (int t = 0; t < 24; ++t){
    int cur = t & 1, nxt = cur ^ 1;
    if (t < 23){ stageA(nxt, (t+1) * 64); stageB(nxt, (t+1) * 64); }
#pragma unroll
    for (int ks = 0; ks < 2; ++ks){
      bf16x8 af[4], bf[9];
#pragma unroll
      for (int j = 0; j < 4; ++j){
        int row = wm + j*16 + fr;
        af[j] = *(const bf16x8*)&As[cur][row*64 + (((ks*4 + g) ^ (row & 7)) << 3)];
      }
#pragma unroll
      for (int ni = 0; ni < 9; ++ni){
        int row = wn + ni*16 + fr;
        bf[ni] = *(const bf16x8*)&Bs[cur][row*64 + (((ks*4 + g) ^ (row & 7)) << 3)];
      }
      __builtin_amdgcn_s_setprio(1);
#pragma unroll
      for (int ni = 0; ni < 9; ++ni){
#pragma unroll
        for (int j = 0; j < 4; ++j)
          acc[j][ni] = __builtin_amdgcn_mfma_f32_16x16x32_bf16(af[j], bf[ni], acc[j][ni], 0, 0, 0);
      }
      __builtin_amdgcn_s_setprio(0);
    }
    if (t < 23) asm volatile("s_waitcnt vmcnt(0)" ::: "memory");
    asm volatile("s_waitcnt lgkmcnt(0)" ::: "memory");
    __builtin_amdgcn_s_barrier();
    asm volatile("" ::: "memory");
  }

#pragma unroll
  for (int mi = 0; mi < 4; ++mi)
#pragma unroll
    for (int ni = 0; ni < 9; ++ni)
#pragma unroll
      for (int rr = 0; rr < 4; ++rr)
        Yt[(size_t)(wm + mi*16 + g*4 + rr) * 4608 + wn + ni*16 + fr] = f2bf(acc[mi][ni][rr]);
}

// ---------- proj GEMM: 128x128, BK=64, dbuf, ONE barrier per K-tile (R15-proven) ----------
__global__ __launch_bounds__(256) void k_gemm_proj(const ushort* __restrict__ AO, const ushort* __restrict__ Wtp,
                                                   float* __restrict__ out){
  __shared__ ushort As[2][8192];
  __shared__ ushort Bs[2][8192];
  int f = blockIdx.x;                      // 384 blocks (= 8*48)
  int nid = (f & 7) * 48 + (f >> 3);
  int z = nid / 96; int rr2 = nid - z * 96;
  int by = rr2 / 12; int bx = rr2 - by * 12;
  int s = z >> 1, bb = z & 1;
  const ushort* A  = AO  + (size_t)(bb*2048 + s*1024 + by*128) * 1536;
  const ushort* Bt = Wtp + (size_t)s * 1536 * 1536 + (size_t)(bx*128) * 1536;
  float* C = out + (size_t)(s*2048 + bb*1024 + by*128) * 1536 + bx*128;
  int tid = threadIdx.x;
  int w = tid >> 6, lane = tid & 63;
  int g = lane >> 4, fr = lane & 15;
  int wm = (w >> 1) * 64, wn = (w & 1) * 64;
  f32x4 acc[4][4] = {};

  auto stage = [&](int b, int kt){
#pragma unroll
    for (int i = 0; i < 4; ++i){
      int c = i * 256 + tid;
      int row = c >> 3, ch = c & 7;
      int src8 = (ch ^ (row & 7)) * 8;
      async16(A  + (size_t)row * 1536 + kt + src8, &As[b][c * 8]);
      async16(Bt + (size_t)row * 1536 + kt + src8, &Bs[b][c * 8]);
    }
  };

  stage(0, 0);
  asm volatile("s_waitcnt vmcnt(0)" ::: "memory");
  __builtin_amdgcn_s_barrier();
  asm volatile("" ::: "memory");

  for (int t = 0; t < 24; ++t){
    int cur = t & 1, nxt = cur ^ 1;
    if (t < 23) stage(nxt, (t+1) * 64);
#pragma unroll
    for (int ks = 0; ks < 2; ++ks){
      bf16x8 af[4], bf[4];
#pragma unroll
      for (int mi = 0; mi < 4; ++mi){
        int row = wm + mi*16 + fr;
        af[mi] = *(const bf16x8*)&As[cur][row*64 + (((ks*4 + g) ^ (row & 7)) << 3)];
      }
#pragma unroll
      for (int ni = 0; ni < 4; ++ni){
        int row = wn + ni*16 + fr;
        bf[ni] = *(const bf16x8*)&Bs[cur][row*64 + (((ks*4 + g) ^ (row & 7)) << 3)];
      }
      __builtin_amdgcn_s_setprio(1);
#pragma unroll
      for (int mi = 0; mi < 4; ++mi)
#pragma unroll
        for (int ni = 0; ni < 4; ++ni)
          acc[mi][ni] = __builtin_amdgcn_mfma_f32_16x16x32_bf16(af[mi], bf[ni], acc[mi][ni], 0, 0, 0);
      __builtin_amdgcn_s_setprio(0);
    }
    if (t < 23) asm volatile("s_waitcnt vmcnt(0)" ::: "memory");
    asm volatile("s_waitcnt lgkmcnt(0)" ::: "memory");
    __builtin_amdgcn_s_barrier();
    asm volatile("" ::: "memory");
  }

  int cr = (lane >> 4) * 4, cc2 = lane & 15;
#pragma unroll
  for (int mi = 0; mi < 4; ++mi)
#pragma unroll
    for (int ni = 0; ni < 4; ++ni)
#pragma unroll
      for (int r = 0; r < 4; ++r)
        C[(size_t)(wm + mi*16 + cr + r) * 1536 + wn + ni*16 + cc2] = acc[mi][ni][r];
}

// ---------- fused RMSNorm + 3D RoPE, LDS-staged coalesced row load (R17-proven) ----------
__global__ __launch_bounds__(256) void k_norm_rope(
    const ushort* __restrict__ Y,
    const float* __restrict__ qn_c, const float* __restrict__ kn_c,
    const float* __restrict__ qn_x, const float* __restrict__ kn_x,
    ushort* __restrict__ Qb, ushort* __restrict__ Kb){
  int r = blockIdx.x;          // row within stream, 0..2047
  int z = blockIdx.y;          // stream: 0 cond, 1 x
  const ushort* y = Y + ((size_t)z * 2048 + r) * 4608;
  const float* qw = z ? qn_x : qn_c;
  const float* kw = z ? kn_x : kn_c;
  int b = r >> 10;
  int l = (z << 10) + (r & 1023);        // joint sequence position
  int tid = threadIdx.x;
  __shared__ uint4 yl4[576];             // staged Q,K portion of the row (4608 ushorts)
  ushort* yl = (ushort*)yl4;
  __shared__ float cs[48], sn[48];
  {
    const uint4* ysrc = (const uint4*)y;
    yl4[tid]       = ysrc[tid];
    yl4[tid + 256] = ysrc[tid + 256];
    if (tid < 64) yl4[tid + 512] = ysrc[tid + 512];
  }
  if (tid < 48){
    int axis = tid >> 4, fj = tid & 15;
    int pos = (axis == 0) ? (l >> 10) : ((axis == 1) ? ((l >> 5) & 31) : (l & 31));
    float inv = __expf(-(float)fj * 0.5756462732485114f);  // 10000^(-fj/16)
    float a = (float)pos * inv;
    sn[tid] = sinf(a); cs[tid] = cosf(a);
  }
  __syncthreads();
  float yq1[3], yq2[3], yk1[3], yk2[3];
  float ssq = 0.f, ssk = 0.f;
#pragma unroll
  for (int i = 0; i < 3; ++i){
    int p = tid + i*256;                 // pair index 0..767
    int head = p / 48, rem = p % 48;
    int c1 = head*96 + (rem >> 4)*32 + (rem & 15);
    float a1 = bf2f(yl[c1]),        a2 = bf2f(yl[c1 + 16]);
    float b1 = bf2f(yl[1536 + c1]), b2 = bf2f(yl[1536 + c1 + 16]);
    yq1[i]=a1; yq2[i]=a2; yk1[i]=b1; yk2[i]=b2;
    ssq += a1*a1 + a2*a2;
    ssk += b1*b1 + b2*b2;
  }
#pragma unroll
  for (int mm = 1; mm < 64; mm <<= 1){
    ssq += __shfl_xor(ssq, mm);
    ssk += __shfl_xor(ssk, mm);
  }
  __shared__ float red[8];
  int w = tid >> 6;
  if ((tid & 63) == 0){ red[w] = ssq; red[4 + w] = ssk; }
  __syncthreads();
  float scq = rsqrtf((red[0]+red[1]+red[2]+red[3]) * (1.f/1536.f) + 1e-6f);
  float sck = rsqrtf((red[4]+red[5]+red[6]+red[7]) * (1.f/1536.f) + 1e-6f);
  float scqS = scq * 0.1020620726159658f;   // fold SCALE = 96^-0.5 into Q (R7-proven; NO log2e)
#pragma unroll
  for (int i = 0; i < 3; ++i){
    int p = tid + i*256;
    int head = p / 48, rem = p % 48;
    int axis = rem >> 4, fj = rem & 15;
    int c1 = head*96 + axis*32 + fj;
    float c = cs[rem], s = sn[rem];
    size_t rowb = ((size_t)(b*16 + head) * 2048 + l) * 96;
    float a1 = yq1[i] * scqS * qw[c1], a2 = yq2[i] * scqS * qw[c1 + 16];
    Qb[rowb + axis*32 + fj]      = f2bf(a1*c - a2*s);
    Qb[rowb + axis*32 + fj + 16] = f2bf(a2*c + a1*s);
    float b1 = yk1[i] * sck * kw[c1], b2 = yk2[i] * sck * kw[c1 + 16];
    int d1 = axis*32 + fj;
    Kb[rowb + d1]      = f2bf(b1*c - b2*s);
    Kb[rowb + d1 + 16] = f2bf(b2*c + b1*s);
  }
}

// ---------- V transpose per head, reading directly from Y: [l][4608] -> [d][2048] ----------
__global__ __launch_bounds__(256) void k_transpose_v(const ushort* __restrict__ Y, ushort* __restrict__ Vt){
  __shared__ ushort t[32][33];
  int bh = blockIdx.z;
  int b = bh >> 4, head = bh & 15;
  int c0 = blockIdx.x * 32;   // d tile within head (0,32,64)
  int l0 = blockIdx.y * 32;   // l tile (32 | 1024 -> never crosses stream boundary)
  int z = l0 >> 10;
  const ushort* src = Y + ((size_t)(z*2048 + b*1024 + (l0 & 1023))) * 4608 + 3072 + head*96 + c0;
  ushort* dst = Vt + (size_t)bh * 96 * 2048;
  int tx = threadIdx.x, ty = threadIdx.y;
  for (int j = 0; j < 4; ++j)
    t[ty + j*8][tx] = src[(size_t)(ty + j*8) * 4608 + tx];
  __syncthreads();
  for (int j = 0; j < 4; ++j)
    dst[(size_t)(c0 + ty + j*8) * 2048 + l0 + tx] = t[tx][ty + j*8];
}

// ---------- flash attention: R13/R15-proven kernel (fmaf-offset exp, VALU denominator) ----------
__global__ __launch_bounds__(256, 2) void k_attn(const ushort* __restrict__ Qb, const ushort* __restrict__ Kb,
                                                 const ushort* __restrict__ Vt, ushort* __restrict__ AO){
  __shared__ ushort Ks[2][6400];   // 64 x (stride 100): bank-step period 16 -> 2-way free on b64
  __shared__ ushort Vs[2][6528];   // 96 x (stride 68), chunk-XOR swizzle
  int id = blockIdx.x;
  int nid = (id & 7) * 64 + (id >> 3);   // XCD-chunked
  int qt = nid & 15, bh = nid >> 4;
  int b = bh >> 4, head = bh & 15;
  const ushort* Qh = Qb + (size_t)bh * 2048 * 96;
  const ushort* Kh = Kb + (size_t)bh * 2048 * 96;
  const ushort* Vh = Vt + (size_t)bh * 96 * 2048;
  int tid = threadIdx.x;
  int w = tid >> 6, lane = tid & 63;
  int h = lane >> 5, c = lane & 31;
  int q0 = qt * 128 + w * 32;

  bf16x8 qf[6];
#pragma unroll
  for (int kb = 0; kb < 6; ++kb)
    qf[kb] = *(const bf16x8*)(Qh + (size_t)(q0 + c) * 96 + kb*16 + h*8);

  int gko[3], lko[3], gvo[3], lvo[3];
#pragma unroll
  for (int i = 0; i < 3; ++i){
    int fc = i*256 + tid;
    int krow = (fc * 683) >> 13;          // /12 exact for fc<2028
    int kc8  = (fc - krow*12) * 8;
    gko[i] = krow*96 + kc8;
    lko[i] = krow*100 + kc8;
    int vrow = fc >> 3;
    int vc8  = (fc & 7) * 8;
    gvo[i] = vrow*2048 + vc8;
    lvo[i] = vrow*68 + (vc8 ^ ((vrow & 7) << 3));   // chunk XOR swizzle
  }
  uint4 kst[3], vst[3];
  f32x16 o[3] = {};
  float dpart = 0.f;
  f32x16 sa[2];

  auto LOADG = [&](int tt){
#pragma unroll
    for (int i = 0; i < 3; ++i){
      kst[i] = *(const uint4*)(Kh + (size_t)tt*6144 + gko[i]);
      vst[i] = *(const uint4*)(Vh + (size_t)tt*64 + gvo[i]);
    }
  };
  auto WRITE = [&](int buf){
#pragma unroll
    for (int i = 0; i < 3; ++i){
      *(uint2*)(&Ks[buf][lko[i]])     = make_uint2(kst[i].x, kst[i].y);
      *(uint2*)(&Ks[buf][lko[i] + 4]) = make_uint2(kst[i].z, kst[i].w);
      *(uint2*)(&Vs[buf][lvo[i]])     = make_uint2(vst[i].x, vst[i].y);
      *(uint2*)(&Vs[buf][lvo[i] + 4]) = make_uint2(vst[i].z, vst[i].w);
    }
  };
  auto QK = [&](f32x16* out, int buf){
#pragma unroll
    for (int ni = 0; ni < 2; ++ni){
      f32x16 a = {};
#pragma unroll
      for (int kb = 0; kb < 6; ++kb){
        const ushort* kp = &Ks[buf][(ni*32 + c)*100 + kb*16 + h*8];
        uint2 lo = *(const uint2*)kp;
        uint2 hi = *(const uint2*)(kp + 4);
        a = __builtin_amdgcn_mfma_f32_32x32x16_bf16(as_bf16x8(lo.x, lo.y, hi.x, hi.y), qf[kb], a, 0, 0, 0);
      }
      out[ni] = a;
    }
  };

  // prologue: KV(0) -> buf0; issue KV(1); QK(0)
  LOADG(0);
  WRITE(0);
  LOADG(1);
  asm volatile("s_waitcnt lgkmcnt(0)" ::: "memory");
  __builtin_amdgcn_s_barrier();
  asm volatile("" ::: "memory");
  QK(sa, 0);

  for (int t = 0; t < 32; ++t){
    int cur = t & 1, nxt = cur ^ 1;
    if (t < 31) WRITE(nxt);            // KV(t+1) regs -> buf[nxt]
    if (t < 30) LOADG(t + 2);          // issue KV(t+2) global loads
    asm volatile("s_waitcnt lgkmcnt(0)" ::: "memory");
    __builtin_amdgcn_s_barrier();
    asm volatile("" ::: "memory");

    // softmax(sa) -> pf  (R7-proven: p = exp2(sa*log2e - 10*log2e); offset cancels in O/den)
    bf16x8 pf[2][2];
#pragma unroll
    for (int ni = 0; ni < 2; ++ni){
      float p[16];
#pragma unroll
      for (int e = 0; e < 16; ++e){
        float x = fmaf(sa[ni][e], 1.44269504f, -14.4269504f);
        asm("v_exp_f32 %0, %1" : "=v"(p[e]) : "v"(x));
      }
      dpart += (((p[0]+p[1])+(p[2]+p[3])) + ((p[4]+p[5])+(p[6]+p[7])))
             + (((p[8]+p[9])+(p[10]+p[11])) + ((p[12]+p[13])+(p[14]+p[15])));
      uint u[8];
#pragma unroll
      for (int e = 0; e < 8; ++e)
        asm("v_cvt_pk_bf16_f32 %0, %1, %2" : "=v"(u[e]) : "v"(p[2*e]), "v"(p[2*e+1]));
      asm("v_permlane32_swap_b32 %0, %1" : "+v"(u[0]), "+v"(u[2]));
      asm("v_permlane32_swap_b32 %0, %1" : "+v"(u[1]), "+v"(u[3]));
      asm("v_permlane32_swap_b32 %0, %1" : "+v"(u[4]), "+v"(u[6]));
      asm("v_permlane32_swap_b32 %0, %1" : "+v"(u[5]), "+v"(u[7]));
      pf[ni][0] = as_bf16x8(u[0], u[1], u[2], u[3]);   // k = ni*32 + [0,16)
      pf[ni][1] = as_bf16x8(u[4], u[5], u[6], u[7]);   // k = ni*32 + [16,32)
    }

    if (t < 31){
      f32x16 na[2];
      QK(na, nxt);                     // QK(t+1) — overlaps softmax above
#pragma unroll
      for (int dt = 0; dt < 3; ++dt)
#pragma unroll
        for (int ni = 0; ni < 2; ++ni)
#pragma unroll
          for (int ks = 0; ks < 2; ++ks){
            int chunk = 4*ni + 2*ks + h;
            const ushort* vp = &Vs[cur][(dt*32 + c)*68 + ((chunk ^ (c & 7)) << 3)];
            uint2 lo = *(const uint2*)vp;
            uint2 hi = *(const uint2*)(vp + 4);
            o[dt] = __builtin_amdgcn_mfma_f32_32x32x16_bf16(pf[ni][ks],
                      as_bf16x8(lo.x, lo.y, hi.x, hi.y), o[dt], 0, 0, 0);
          }
      sa[0] = na[0]; sa[1] = na[1];
    } else {
#pragma unroll
      for (int dt = 0; dt < 3; ++dt)
#pragma unroll
        for (int ni = 0; ni < 2; ++ni)
#pragma unroll
          for (int ks = 0; ks < 2; ++ks){
            int chunk = 4*ni + 2*ks + h;
            const ushort* vp = &Vs[cur][(dt*32 + c)*68 + ((chunk ^ (c & 7)) << 3)];
            uint2 lo = *(const uint2*)vp;
            uint2 hi = *(const uint2*)(vp + 4);
            o[dt] = __builtin_amdgcn_mfma_f32_32x32x16_bf16(pf[ni][ks],
                      as_bf16x8(lo.x, lo.y, hi.x, hi.y), o[dt], 0, 0, 0);
          }
    }
    asm volatile("" ::: "memory");
    __builtin_amdgcn_s_barrier();
    asm volatile("" ::: "memory");
  }

  float dtot = dpart + __shfl_xor(dpart, 32);
#pragma unroll
  for (int r = 0; r < 16; ++r){
    int qloc = (r & 3) + 8*(r >> 2) + 4*h;
    float den = __shfl(dtot, qloc);
    float dinv = __builtin_amdgcn_rcpf(den);
    size_t rowoff = ((size_t)b * 2048 + q0 + qloc) * 1536 + head * 96;
#pragma unroll
    for (int dt = 0; dt < 3; ++dt){
      float val = o[dt][r] * dinv;
      uint pk; asm("v_cvt_pk_bf16_f32 %0, %1, %2" : "=v"(pk) : "v"(val), "v"(val));
      AO[rowoff + dt*32 + c] = (ushort)pk;
    }
  }
}

extern "C" void kernel_launch(void* const* d_in, const int* in_sizes, int n_in,
                              void* d_out, int out_size, void* d_ws, size_t ws_size,
                              hipStream_t stream){
  const float* cond = (const float*)d_in[0];
  const float* x    = (const float*)d_in[1];
  const float* wq_c = (const float*)d_in[2];
  const float* wk_c = (const float*)d_in[3];
  const float* wv_c = (const float*)d_in[4];
  const float* qn_c = (const float*)d_in[5];
  const float* kn_c = (const float*)d_in[6];
  const float* wp_c = (const float*)d_in[7];
  const float* wq_x = (const float*)d_in[8];
  const float* wk_x = (const float*)d_in[9];
  const float* wv_x = (const float*)d_in[10];
  const float* qn_x = (const float*)d_in[11];
  const float* kn_x = (const float*)d_in[12];
  const float* wp_x = (const float*)d_in[13];

  char* ws = (char*)d_ws;
  ushort* inb = (ushort*)(ws);                 // [2][2048][1536] bf16 (later reused as AO)
  ushort* Wt  = (ushort*)(ws + 12582912ll);    // [12288][1536] bf16 (qkv_c, qkv_x, proj_c, proj_x)
  ushort* Y   = (ushort*)(ws + 50331648ll);    // [2][2048][4608] bf16
  ushort* Qb  = (ushort*)(ws + 88080384ll);    // [32][2048][96] (SCALE folded)
  ushort* Kb  = (ushort*)(ws + 100663296ll);   // [32][2048][96] plain
  ushort* Vt  = (ushort*)(ws + 113246208ll);   // [32][96][2048]
  ushort* AO  = inb;                           // [2][2048][1536] bf16 plain

  k_conv_in<<<3072, 256, 0, stream>>>(cond, x, inb);
  k_transpose_w<<<dim3(48,48,8), dim3(32,8), 0, stream>>>(wq_c, wk_c, wv_c, wq_x, wk_x, wv_x, wp_c, wp_x, Wt);
  k_gemm_qkv<<<256, 512, 0, stream>>>(inb, Wt, Y);
  k_norm_rope<<<dim3(2048,2), 256, 0, stream>>>(Y, qn_c, kn_c, qn_x, kn_x, Qb, Kb);
  k_transpose_v<<<dim3(3,64,32), dim3(32,8), 0, stream>>>(Y, Vt);
  k_attn<<<512, 256, 0, stream>>>(Qb, Kb, Vt, AO);
  k_gemm_proj<<<384, 256, 0, stream>>>(AO, Wt + (size_t)9216*1536, (float*)d_out);
  (void)in_sizes; (void)n_in; (void)out_size; (void)ws_size;
}